// Round 7
// baseline (3352.253 us; speedup 1.0000x reference)
//
#include <hip/hip_runtime.h>

#define BB 256
#define TT 2048
#define SS 32
#define NN 19
#define NCLASS 10
#define NUNFOLD 6
#define EPSV 1e-8f
#define LOG2E 1.4426950408889634f

typedef float f32x2 __attribute__((ext_vector_type(2)));

__device__ __forceinline__ f32x2 pk_fma(f32x2 a, f32x2 b, f32x2 c)
{
#if __has_builtin(__builtin_elementwise_fma)
    return __builtin_elementwise_fma(a, b, c);
#else
    return (f32x2){fmaf(a.x, b.x, c.x), fmaf(a.y, b.y, c.y)};
#endif
}
__device__ __forceinline__ f32x2 splat2(float s) { return (f32x2){s, s}; }

// ---------------------------------------------------------------------------
// Phase 1: sensory precompute (kept from R6 — non-scan time 458->270us).
// Thread = (t,b) computing all 19 outputs; params staged in LDS per block.
// ---------------------------------------------------------------------------
__global__ void __launch_bounds__(256)
ltc_sens_kernel(const float* __restrict__ x,
                const float* __restrict__ iw,
                const float* __restrict__ ib,
                const float* __restrict__ smu,
                const float* __restrict__ ssig,
                const float* __restrict__ sw,
                const float* __restrict__ serev,
                const int* __restrict__ smask,
                float* __restrict__ sens,
                int t0, int tc)
{
    __shared__ float4 pq[SS * NN];            // {P, Qn, W, A} per (s,j)
    int tid = threadIdx.x;
    for (int idx = tid; idx < SS * NN; idx += 256) {
        int s = idx / NN;                     // idx = s*NN + j
        float sg = ssig[idx] * LOG2E;
        float P  = sg * smu[idx] - sg * ib[s];
        float Qn = -sg * iw[s];
        float wm = sw[idx] * (float)smask[idx];
        pq[idx] = make_float4(P, Qn, wm, wm * serev[idx]);
    }
    __syncthreads();

    long gid = (long)blockIdx.x * 256 + tid;
    if (gid >= (long)tc * BB) return;
    int trel = (int)(gid % tc);
    int b    = (int)(gid / tc);
    int t    = t0 + trel;

    float xs[SS];
    const float4* xr4 = (const float4*)(x + ((long)b * TT + t) * SS);
#pragma unroll
    for (int q = 0; q < SS / 4; q++) {
        float4 v4 = xr4[q];
        xs[4 * q + 0] = v4.x; xs[4 * q + 1] = v4.y;
        xs[4 * q + 2] = v4.z; xs[4 * q + 3] = v4.w;
    }

    float* o = sens + ((long)trel * BB + b) * (2 * NN);
    for (int j = 0; j < NN; j++) {
        f32x2 nd = {0.f, 0.f};
#pragma unroll 4
        for (int s = 0; s < SS; s += 2) {
            float4 c0 = pq[s * NN + j];
            float4 c1 = pq[(s + 1) * NN + j];
            float e0 = __builtin_amdgcn_exp2f(fmaf(c0.y, xs[s], c0.x));
            float e1 = __builtin_amdgcn_exp2f(fmaf(c1.y, xs[s + 1], c1.x));
            f32x2 tv = (f32x2){e0, e1} + 1.0f;
            float rD = __builtin_amdgcn_rcpf(tv.x * tv.y);
            f32x2 aw0 = {c0.w, c0.z};         // {A, W}
            f32x2 aw1 = {c1.w, c1.z};
            f32x2 npq = pk_fma(aw1, splat2(tv.x), aw0 * splat2(tv.y));
            nd = pk_fma(npq, splat2(rD), nd);
        }
        o[j]      = nd.x;
        o[NN + j] = nd.y;
    }
}

// ---------------------------------------------------------------------------
template <int CTRL>
__device__ __forceinline__ float dpp_shl(float x)
{
    return __int_as_float(__builtin_amdgcn_update_dpp(
        0, __float_as_int(x), CTRL, 0xf, 0xf, true));
}

__device__ __forceinline__ float bperm(int addr4, float v)
{
    return __int_as_float(__builtin_amdgcn_ds_bpermute(addr4, __float_as_int(v)));
}

// leader lane of pre-neuron i (rows 2,3 offset +1 => all 19 leaders in
// distinct LDS banks -> conflict-free bpermute broadcast)
__device__ __forceinline__ int lead_lane(int i)
{
    int rw = i / 5;
    return 16 * rw + 3 * (i % 5) + (rw >= 2 ? 1 : 0);
}

// ---------------------------------------------------------------------------
// Templated scan main loop: TWO independent batch chains per wave (ILP fills
// single-wave dependent-stall slots; the per-unfold LDS round trip is paid
// once for both).  Scalar math = R5 form (R6's packed form regressed).
// Conflict-free leader banks => SQ_LDS_BANK_CONFLICT stays 0.
// ---------------------------------------------------------------------------
template <int KU>
__device__ __forceinline__ void run_scan2(
    int lane, int jc, bool pad, int r,
    const float (&sg2)[8], const float (&sb2)[8],
    const float (&Aa)[8], const float (&Wm)[8], const int (&src4)[8],
    float cmt, float glvl, float cgl, float ow0, float ob0,
    const float* __restrict__ sens, float* __restrict__ outbuf,
    float* __restrict__ vstate, int b0, int t0, int tc, int initv)
{
    float v0 = initv ? 0.f : vstate[b0 * NN + jc];
    float v1 = initv ? 0.f : vstate[(b0 + 1) * NN + jc];
    const float* sp0 = sens + (long)b0 * (2 * NN);
    const float* sp1 = sens + (long)(b0 + 1) * (2 * NN);
    float sn0 = sp0[jc], sd0 = sp0[NN + jc];
    float sn1 = sp1[jc], sd1 = sp1[NN + jc];

    for (int t = 0; t < tc; t++) {
        float sn0n = sn0, sd0n = sd0, sn1n = sn1, sd1n = sd1;
        if (t + 1 < tc) {
            const float* q0 = sens + ((long)(t + 1) * BB + b0) * (2 * NN);
            const float* q1 = sens + ((long)(t + 1) * BB + b0 + 1) * (2 * NN);
            sn0n = q0[jc]; sd0n = q0[NN + jc];
            sn1n = q1[jc]; sd1n = q1[NN + jc];
        }
        float nb0 = glvl + sn0, db0 = cgl + sd0;
        float nb1 = glvl + sn1, db1 = cgl + sd1;

#pragma unroll
        for (int u = 0; u < NUNFOLD; u++) {
            // all bpermutes issued back-to-back: latencies overlap both chains
            float vi0[KU], vi1[KU];
#pragma unroll
            for (int k = 0; k < KU; k++) vi0[k] = bperm(src4[k], v0);
#pragma unroll
            for (int k = 0; k < KU; k++) vi1[k] = bperm(src4[k], v1);

            float n0 = fmaf(cmt, v0, nb0);
            float n1 = fmaf(cmt, v1, nb1);

            float e0[KU], e1[KU];
#pragma unroll
            for (int k = 0; k < KU; k++)
                e0[k] = __builtin_amdgcn_exp2f(fmaf(sg2[k], vi0[k], sb2[k]));
#pragma unroll
            for (int k = 0; k < KU; k++)
                e1[k] = __builtin_amdgcn_exp2f(fmaf(sg2[k], vi1[k], sb2[k]));

            float pn0 = 0.f, pd0 = 0.f, pn1 = 0.f, pd1 = 0.f;
            constexpr int NP = KU / 2;
#pragma unroll
            for (int p = 0; p < NP; p++) {
                float a0 = 1.0f + e0[2 * p], a1 = 1.0f + e0[2 * p + 1];
                float rA = __builtin_amdgcn_rcpf(a0 * a1);
                pn0 = fmaf(fmaf(Aa[2 * p], a1, Aa[2 * p + 1] * a0), rA, pn0);
                pd0 = fmaf(fmaf(Wm[2 * p], a1, Wm[2 * p + 1] * a0), rA, pd0);
                float c0 = 1.0f + e1[2 * p], c1 = 1.0f + e1[2 * p + 1];
                float rC = __builtin_amdgcn_rcpf(c0 * c1);
                pn1 = fmaf(fmaf(Aa[2 * p], c1, Aa[2 * p + 1] * c0), rC, pn1);
                pd1 = fmaf(fmaf(Wm[2 * p], c1, Wm[2 * p + 1] * c0), rC, pd1);
            }
            if (KU & 1) {
                float s0 = __builtin_amdgcn_rcpf(1.0f + e0[KU - 1]);
                float s1 = __builtin_amdgcn_rcpf(1.0f + e1[KU - 1]);
                pn0 = fmaf(Aa[KU - 1], s0, pn0); pd0 = fmaf(Wm[KU - 1], s0, pd0);
                pn1 = fmaf(Aa[KU - 1], s1, pn1); pd1 = fmaf(Wm[KU - 1], s1, pd1);
            }

            // 3-lane DPP reduce: triple base lane gets the full sum
            pn0 = pn0 + dpp_shl<0x101>(pn0) + dpp_shl<0x102>(pn0);
            pd0 = pd0 + dpp_shl<0x101>(pd0) + dpp_shl<0x102>(pd0);
            pn1 = pn1 + dpp_shl<0x101>(pn1) + dpp_shl<0x102>(pn1);
            pd1 = pd1 + dpp_shl<0x101>(pd1) + dpp_shl<0x102>(pd1);

            v0 = (n0 + pn0) * __builtin_amdgcn_rcpf(db0 + pd0);
            v1 = (n1 + pn1) * __builtin_amdgcn_rcpf(db1 + pd1);
        }
        if (lane == 0) {
            outbuf[(long)b0 * TT + (t0 + t)]       = fmaf(v0, ow0, ob0);
            outbuf[(long)(b0 + 1) * TT + (t0 + t)] = fmaf(v1, ow0, ob0);
        }
        sn0 = sn0n; sd0 = sd0n; sn1 = sn1n; sd1 = sd1n;
    }
    if (!pad && r == 0) {
        vstate[b0 * NN + jc]       = v0;
        vstate[(b0 + 1) * NN + jc] = v1;
    }
}

// ---------------------------------------------------------------------------
// Phase 2 kernel: balanced sparse slot lists (mask ~50% zero), wave-uniform
// KU dispatch, two batches per wave.
// ---------------------------------------------------------------------------
__global__ void __launch_bounds__(64, 1)
ltc_scan_kernel(const float* __restrict__ mu,  const float* __restrict__ sigma,
                const float* __restrict__ w,   const float* __restrict__ erev,
                const int* __restrict__ mask,
                const float* __restrict__ gleak, const float* __restrict__ vleak,
                const float* __restrict__ cm,
                const float* __restrict__ ow,  const float* __restrict__ ob,
                const float* __restrict__ sens, float* __restrict__ outbuf,
                float* __restrict__ vstate, int t0, int tc, int initv)
{
    int b0   = blockIdx.x * 2;
    int lane = threadIdx.x;
    int row  = lane >> 4;
    int pos  = lane & 15;
    int off  = (row >= 2) ? 1 : 0;
    int posr = pos - off;                       // row>=2: pos 0 is pad
    int jq   = (posr < 0) ? 5 : posr / 3;       // 5 => pad
    int rr   = (posr < 0) ? 0 : posr - 3 * jq;
    int j    = row * 5 + jq;
    bool pad = (jq >= 5) || (j >= NN);
    int jc   = pad ? 0 : j;
    int r    = pad ? 0 : rr;

    // balanced sparse slot lists: the a-th active pre-neuron of column j goes
    // to lane r = a%3, slot a/3.  Dummy slots: weights 0 (exact).
    float sg2[8], sb2[8], Aa[8], Wm[8];
    int src4[8];
    int used = 0;
#pragma unroll
    for (int s = 0; s < 8; s++) {
        int target = 3 * s + r;
        int ii = -1, a = 0;
        for (int i = 0; i < NN; i++) {
            if (mask[i * NN + jc] != 0) {
                if (a == target) ii = i;
                a++;
            }
        }
        bool ok = (ii >= 0) && !pad;
        int iu  = ok ? ii : 0;
        int idx = iu * NN + jc;
        float sgv = sigma[idx];
        float wmm = ok ? w[idx] : 0.f;          // mask[idx]==1 when ok
        sg2[s] = ok ? (-LOG2E * sgv) : 0.f;
        sb2[s] = ok ? (LOG2E * sgv * mu[idx]) : 0.f;
        Aa[s]  = wmm * erev[idx];
        Wm[s]  = wmm;
        src4[s] = lead_lane(iu) << 2;
        if (ok) used = s + 1;
    }

    // wave-max of used slots (prologue-only shuffles)
    int km = used;
#pragma unroll
    for (int o = 1; o < 64; o <<= 1) {
        int other = __shfl_xor(km, o, 64);
        km = km > other ? km : other;
    }

    float cmt   = cm[jc] * (float)NUNFOLD;
    float gl    = gleak[jc];
    float glvl  = gl * vleak[jc];
    float cgl   = cmt + gl + EPSV;
    float ow0 = ow[0], ob0 = ob[0];

    if (km <= 3)
        run_scan2<3>(lane, jc, pad, r, sg2, sb2, Aa, Wm, src4, cmt, glvl, cgl,
                     ow0, ob0, sens, outbuf, vstate, b0, t0, tc, initv);
    else if (km == 4)
        run_scan2<4>(lane, jc, pad, r, sg2, sb2, Aa, Wm, src4, cmt, glvl, cgl,
                     ow0, ob0, sens, outbuf, vstate, b0, t0, tc, initv);
    else if (km == 5)
        run_scan2<5>(lane, jc, pad, r, sg2, sb2, Aa, Wm, src4, cmt, glvl, cgl,
                     ow0, ob0, sens, outbuf, vstate, b0, t0, tc, initv);
    else if (km == 6)
        run_scan2<6>(lane, jc, pad, r, sg2, sb2, Aa, Wm, src4, cmt, glvl, cgl,
                     ow0, ob0, sens, outbuf, vstate, b0, t0, tc, initv);
    else
        run_scan2<7>(lane, jc, pad, r, sg2, sb2, Aa, Wm, src4, cmt, glvl, cgl,
                     ow0, ob0, sens, outbuf, vstate, b0, t0, tc, initv);
}

// ---------------------------------------------------------------------------
// Phase 3: FC head.  One wave per (b, c).
// ---------------------------------------------------------------------------
__global__ void ltc_fc_kernel(const float* __restrict__ outbuf,
                              const float* __restrict__ fcw,
                              const float* __restrict__ fcb,
                              float* __restrict__ out)
{
    int bc = blockIdx.x;
    int b = bc / NCLASS;
    int c = bc % NCLASS;
    const float* xr = outbuf + (long)b * TT;
    const float* wr = fcw + (long)c * TT;
    float acc = 0.f;
    for (int t = threadIdx.x; t < TT; t += 64)
        acc = fmaf(xr[t], wr[t], acc);
#pragma unroll
    for (int off = 32; off > 0; off >>= 1)
        acc += __shfl_down(acc, off, 64);
    if (threadIdx.x == 0) out[bc] = acc + fcb[c];
}

// ---------------------------------------------------------------------------
extern "C" void kernel_launch(void* const* d_in, const int* in_sizes, int n_in,
                              void* d_out, int out_size, void* d_ws, size_t ws_size,
                              hipStream_t stream)
{
    const float* x     = (const float*)d_in[0];
    const float* iw    = (const float*)d_in[1];
    const float* ib    = (const float*)d_in[2];
    const float* smu   = (const float*)d_in[3];
    const float* ssig  = (const float*)d_in[4];
    const float* sw    = (const float*)d_in[5];
    const float* serev = (const float*)d_in[6];
    const float* mu    = (const float*)d_in[7];
    const float* sigma = (const float*)d_in[8];
    const float* w     = (const float*)d_in[9];
    const float* erev  = (const float*)d_in[10];
    const float* gleak = (const float*)d_in[11];
    const float* vleak = (const float*)d_in[12];
    const float* cm    = (const float*)d_in[13];
    const float* ow    = (const float*)d_in[14];
    const float* ob    = (const float*)d_in[15];
    const float* fcw   = (const float*)d_in[16];
    const float* fcb   = (const float*)d_in[17];
    const int* smask   = (const int*)d_in[18];
    const int* mask    = (const int*)d_in[19];
    float* out = (float*)d_out;

    // ws layout: [outbuf: B*T f32][vstate: B*N f32][sens: Tc*B*2N f32]
    float* outbuf = (float*)d_ws;
    float* vstate = outbuf + (long)BB * TT;
    float* sens   = vstate + (long)BB * NN;

    size_t fixed = ((size_t)BB * TT + (size_t)BB * NN) * sizeof(float);
    long avail = (long)ws_size - (long)fixed;
    long per_step = (long)BB * 2 * NN * sizeof(float);
    int Tc = (int)(avail / per_step);
    if (Tc > TT) Tc = TT;
    if (Tc < 1)  Tc = 1;

    for (int t0 = 0; t0 < TT; t0 += Tc) {
        int tc = (TT - t0 < Tc) ? (TT - t0) : Tc;
        long total = (long)tc * BB;
        int blocks = (int)((total + 255) / 256);
        ltc_sens_kernel<<<blocks, 256, 0, stream>>>(x, iw, ib, smu, ssig, sw,
                                                    serev, smask, sens, t0, tc);
        ltc_scan_kernel<<<BB / 2, 64, 0, stream>>>(mu, sigma, w, erev, mask, gleak,
                                                   vleak, cm, ow, ob, sens, outbuf,
                                                   vstate, t0, tc, t0 == 0 ? 1 : 0);
    }
    ltc_fc_kernel<<<BB * NCLASS, 64, 0, stream>>>(outbuf, fcw, fcb, out);
}

// Round 8
// 2153.753 us; speedup vs baseline: 1.5565x; 1.5565x over previous
//
#include <hip/hip_runtime.h>

#define BB 256
#define TT 2048
#define SS 32
#define NN 19
#define NCLASS 10
#define NUNFOLD 6
#define EPSV 1e-8f
#define LOG2E 1.4426950408889634f

typedef float f32x2 __attribute__((ext_vector_type(2)));

__device__ __forceinline__ f32x2 pk_fma(f32x2 a, f32x2 b, f32x2 c)
{
#if __has_builtin(__builtin_elementwise_fma)
    return __builtin_elementwise_fma(a, b, c);
#else
    return (f32x2){fmaf(a.x, b.x, c.x), fmaf(a.y, b.y, c.y)};
#endif
}
__device__ __forceinline__ f32x2 splat2(float s) { return (f32x2){s, s}; }

// ---------------------------------------------------------------------------
// Phase 1: sensory precompute (R6 version — measured non-scan 270us).
// Thread = (t,b) computing all 19 outputs; params staged in LDS per block.
// ---------------------------------------------------------------------------
__global__ void __launch_bounds__(256)
ltc_sens_kernel(const float* __restrict__ x,
                const float* __restrict__ iw,
                const float* __restrict__ ib,
                const float* __restrict__ smu,
                const float* __restrict__ ssig,
                const float* __restrict__ sw,
                const float* __restrict__ serev,
                const int* __restrict__ smask,
                float* __restrict__ sens,
                int t0, int tc)
{
    __shared__ float4 pq[SS * NN];            // {P, Qn, W, A} per (s,j)
    int tid = threadIdx.x;
    for (int idx = tid; idx < SS * NN; idx += 256) {
        int s = idx / NN;                     // idx = s*NN + j
        float sg = ssig[idx] * LOG2E;
        float P  = sg * smu[idx] - sg * ib[s];
        float Qn = -sg * iw[s];
        float wm = sw[idx] * (float)smask[idx];
        pq[idx] = make_float4(P, Qn, wm, wm * serev[idx]);
    }
    __syncthreads();

    long gid = (long)blockIdx.x * 256 + tid;
    if (gid >= (long)tc * BB) return;
    int trel = (int)(gid % tc);
    int b    = (int)(gid / tc);
    int t    = t0 + trel;

    float xs[SS];
    const float4* xr4 = (const float4*)(x + ((long)b * TT + t) * SS);
#pragma unroll
    for (int q = 0; q < SS / 4; q++) {
        float4 v4 = xr4[q];
        xs[4 * q + 0] = v4.x; xs[4 * q + 1] = v4.y;
        xs[4 * q + 2] = v4.z; xs[4 * q + 3] = v4.w;
    }

    float* o = sens + ((long)trel * BB + b) * (2 * NN);
    for (int j = 0; j < NN; j++) {
        f32x2 nd = {0.f, 0.f};
#pragma unroll 4
        for (int s = 0; s < SS; s += 2) {
            float4 c0 = pq[s * NN + j];
            float4 c1 = pq[(s + 1) * NN + j];
            float e0 = __builtin_amdgcn_exp2f(fmaf(c0.y, xs[s], c0.x));
            float e1 = __builtin_amdgcn_exp2f(fmaf(c1.y, xs[s + 1], c1.x));
            f32x2 tv = (f32x2){e0, e1} + 1.0f;
            float rD = __builtin_amdgcn_rcpf(tv.x * tv.y);
            f32x2 aw0 = {c0.w, c0.z};         // {A, W}
            f32x2 aw1 = {c1.w, c1.z};
            f32x2 npq = pk_fma(aw1, splat2(tv.x), aw0 * splat2(tv.y));
            nd = pk_fma(npq, splat2(rD), nd);
        }
        o[j]      = nd.x;
        o[NN + j] = nd.y;
    }
}

// ---------------------------------------------------------------------------
template <int CTRL>
__device__ __forceinline__ float dpp_shl(float x)
{
    return __int_as_float(__builtin_amdgcn_update_dpp(
        0, __float_as_int(x), CTRL, 0xf, 0xf, true));
}

__device__ __forceinline__ float bperm(int addr4, float v)
{
    return __int_as_float(__builtin_amdgcn_ds_bpermute(addr4, __float_as_int(v)));
}

// leader lane of pre-neuron i (rows 2,3 offset +1 => all 19 leaders in
// distinct LDS banks -> conflict-free bpermute broadcast)
__device__ __forceinline__ int lead_lane(int i)
{
    int rw = i / 5;
    return 16 * rw + 3 * (i % 5) + (rw >= 2 ? 1 : 0);
}

// ---------------------------------------------------------------------------
// Templated scan main loop — exact R5 structure (measured best: 1888us,
// ~368 cy/unfold).  One batch per wave, scalar math, sparse slots.
// ---------------------------------------------------------------------------
template <int KU>
__device__ __forceinline__ void run_scan(
    int lane, int jc, bool pad, int r,
    const float (&sg2)[8], const float (&sb2)[8],
    const float (&Aa)[8], const float (&Wm)[8], const int (&src4)[8],
    float cmt, float glvl, float cgl, float ow0, float ob0,
    const float* __restrict__ sens, float* __restrict__ outbuf,
    float* __restrict__ vstate, int b, int t0, int tc, int initv)
{
    float v = initv ? 0.f : vstate[b * NN + jc];
    const float* sp0 = sens + (long)b * (2 * NN);
    float sn = sp0[jc], sd = sp0[NN + jc];

    for (int t = 0; t < tc; t++) {
        float sn_nx = sn, sd_nx = sd;
        if (t + 1 < tc) {
            const float* spn = sens + ((long)(t + 1) * BB + b) * (2 * NN);
            sn_nx = spn[jc]; sd_nx = spn[NN + jc];
        }
        float nbase = glvl + sn, dbase = cgl + sd;

#pragma unroll
        for (int u = 0; u < NUNFOLD; u++) {
            float vi[KU];
#pragma unroll
            for (int k = 0; k < KU; k++) vi[k] = bperm(src4[k], v);

            float n = fmaf(cmt, v, nbase);

            float ev[KU];
#pragma unroll
            for (int k = 0; k < KU; k++)
                ev[k] = __builtin_amdgcn_exp2f(fmaf(sg2[k], vi[k], sb2[k]));

            float pn = 0.f, pd = 0.f;
            constexpr int NP = KU / 2;
#pragma unroll
            for (int p = 0; p < NP; p++) {
                float t0v = 1.0f + ev[2 * p];
                float t1v = 1.0f + ev[2 * p + 1];
                float rD  = __builtin_amdgcn_rcpf(t0v * t1v);
                pn = fmaf(fmaf(Aa[2 * p], t1v, Aa[2 * p + 1] * t0v), rD, pn);
                pd = fmaf(fmaf(Wm[2 * p], t1v, Wm[2 * p + 1] * t0v), rD, pd);
            }
            if (KU & 1) {
                float s1 = __builtin_amdgcn_rcpf(1.0f + ev[KU - 1]);
                pn = fmaf(Aa[KU - 1], s1, pn);
                pd = fmaf(Wm[KU - 1], s1, pd);
            }

            // 3-lane DPP reduce: triple base lane gets the full sum
            pn = pn + dpp_shl<0x101>(pn) + dpp_shl<0x102>(pn);
            pd = pd + dpp_shl<0x101>(pd) + dpp_shl<0x102>(pd);

            // all lanes update; only leader lanes are ever read (bperm/store)
            v = (n + pn) * __builtin_amdgcn_rcpf(dbase + pd);
        }
        if (lane == 0) outbuf[(long)b * TT + (t0 + t)] = fmaf(v, ow0, ob0);
        sn = sn_nx; sd = sd_nx;
    }
    if (!pad && r == 0) vstate[b * NN + jc] = v;
}

// ---------------------------------------------------------------------------
// Phase 2 kernel: balanced sparse slot lists (mask ~50% zero), wave-uniform
// KU dispatch, ONE batch per wave (dual-chain measured worse: R7).
// ---------------------------------------------------------------------------
__global__ void __launch_bounds__(64, 1)
ltc_scan_kernel(const float* __restrict__ mu,  const float* __restrict__ sigma,
                const float* __restrict__ w,   const float* __restrict__ erev,
                const int* __restrict__ mask,
                const float* __restrict__ gleak, const float* __restrict__ vleak,
                const float* __restrict__ cm,
                const float* __restrict__ ow,  const float* __restrict__ ob,
                const float* __restrict__ sens, float* __restrict__ outbuf,
                float* __restrict__ vstate, int t0, int tc, int initv)
{
    int b    = blockIdx.x;
    int lane = threadIdx.x;
    int row  = lane >> 4;
    int pos  = lane & 15;
    int off  = (row >= 2) ? 1 : 0;
    int posr = pos - off;                       // row>=2: pos 0 is pad
    int jq   = (posr < 0) ? 5 : posr / 3;       // 5 => pad
    int rr   = (posr < 0) ? 0 : posr - 3 * jq;
    int j    = row * 5 + jq;
    bool pad = (jq >= 5) || (j >= NN);
    int jc   = pad ? 0 : j;
    int r    = pad ? 0 : rr;

    // balanced sparse slot lists: the a-th active pre-neuron of column j goes
    // to lane r = a%3, slot a/3.  Dummy slots: weights 0 (exact).
    float sg2[8], sb2[8], Aa[8], Wm[8];
    int src4[8];
    int used = 0;
#pragma unroll
    for (int s = 0; s < 8; s++) {
        int target = 3 * s + r;
        int ii = -1, a = 0;
        for (int i = 0; i < NN; i++) {
            if (mask[i * NN + jc] != 0) {
                if (a == target) ii = i;
                a++;
            }
        }
        bool ok = (ii >= 0) && !pad;
        int iu  = ok ? ii : 0;
        int idx = iu * NN + jc;
        float sgv = sigma[idx];
        float wmm = ok ? w[idx] : 0.f;          // mask[idx]==1 when ok
        sg2[s] = ok ? (-LOG2E * sgv) : 0.f;
        sb2[s] = ok ? (LOG2E * sgv * mu[idx]) : 0.f;
        Aa[s]  = wmm * erev[idx];
        Wm[s]  = wmm;
        src4[s] = lead_lane(iu) << 2;
        if (ok) used = s + 1;
    }

    // wave-max of used slots (prologue-only shuffles)
    int km = used;
#pragma unroll
    for (int o = 1; o < 64; o <<= 1) {
        int other = __shfl_xor(km, o, 64);
        km = km > other ? km : other;
    }

    float cmt   = cm[jc] * (float)NUNFOLD;
    float gl    = gleak[jc];
    float glvl  = gl * vleak[jc];
    float cgl   = cmt + gl + EPSV;
    float ow0 = ow[0], ob0 = ob[0];

    if (km <= 3)
        run_scan<3>(lane, jc, pad, r, sg2, sb2, Aa, Wm, src4, cmt, glvl, cgl,
                    ow0, ob0, sens, outbuf, vstate, b, t0, tc, initv);
    else if (km == 4)
        run_scan<4>(lane, jc, pad, r, sg2, sb2, Aa, Wm, src4, cmt, glvl, cgl,
                    ow0, ob0, sens, outbuf, vstate, b, t0, tc, initv);
    else if (km == 5)
        run_scan<5>(lane, jc, pad, r, sg2, sb2, Aa, Wm, src4, cmt, glvl, cgl,
                    ow0, ob0, sens, outbuf, vstate, b, t0, tc, initv);
    else if (km == 6)
        run_scan<6>(lane, jc, pad, r, sg2, sb2, Aa, Wm, src4, cmt, glvl, cgl,
                    ow0, ob0, sens, outbuf, vstate, b, t0, tc, initv);
    else
        run_scan<7>(lane, jc, pad, r, sg2, sb2, Aa, Wm, src4, cmt, glvl, cgl,
                    ow0, ob0, sens, outbuf, vstate, b, t0, tc, initv);
}

// ---------------------------------------------------------------------------
// Phase 3: FC head.  One wave per (b, c).
// ---------------------------------------------------------------------------
__global__ void ltc_fc_kernel(const float* __restrict__ outbuf,
                              const float* __restrict__ fcw,
                              const float* __restrict__ fcb,
                              float* __restrict__ out)
{
    int bc = blockIdx.x;
    int b = bc / NCLASS;
    int c = bc % NCLASS;
    const float* xr = outbuf + (long)b * TT;
    const float* wr = fcw + (long)c * TT;
    float acc = 0.f;
    for (int t = threadIdx.x; t < TT; t += 64)
        acc = fmaf(xr[t], wr[t], acc);
#pragma unroll
    for (int off = 32; off > 0; off >>= 1)
        acc += __shfl_down(acc, off, 64);
    if (threadIdx.x == 0) out[bc] = acc + fcb[c];
}

// ---------------------------------------------------------------------------
extern "C" void kernel_launch(void* const* d_in, const int* in_sizes, int n_in,
                              void* d_out, int out_size, void* d_ws, size_t ws_size,
                              hipStream_t stream)
{
    const float* x     = (const float*)d_in[0];
    const float* iw    = (const float*)d_in[1];
    const float* ib    = (const float*)d_in[2];
    const float* smu   = (const float*)d_in[3];
    const float* ssig  = (const float*)d_in[4];
    const float* sw    = (const float*)d_in[5];
    const float* serev = (const float*)d_in[6];
    const float* mu    = (const float*)d_in[7];
    const float* sigma = (const float*)d_in[8];
    const float* w     = (const float*)d_in[9];
    const float* erev  = (const float*)d_in[10];
    const float* gleak = (const float*)d_in[11];
    const float* vleak = (const float*)d_in[12];
    const float* cm    = (const float*)d_in[13];
    const float* ow    = (const float*)d_in[14];
    const float* ob    = (const float*)d_in[15];
    const float* fcw   = (const float*)d_in[16];
    const float* fcb   = (const float*)d_in[17];
    const int* smask   = (const int*)d_in[18];
    const int* mask    = (const int*)d_in[19];
    float* out = (float*)d_out;

    // ws layout: [outbuf: B*T f32][vstate: B*N f32][sens: Tc*B*2N f32]
    float* outbuf = (float*)d_ws;
    float* vstate = outbuf + (long)BB * TT;
    float* sens   = vstate + (long)BB * NN;

    size_t fixed = ((size_t)BB * TT + (size_t)BB * NN) * sizeof(float);
    long avail = (long)ws_size - (long)fixed;
    long per_step = (long)BB * 2 * NN * sizeof(float);
    int Tc = (int)(avail / per_step);
    if (Tc > TT) Tc = TT;
    if (Tc < 1)  Tc = 1;

    for (int t0 = 0; t0 < TT; t0 += Tc) {
        int tc = (TT - t0 < Tc) ? (TT - t0) : Tc;
        long total = (long)tc * BB;
        int blocks = (int)((total + 255) / 256);
        ltc_sens_kernel<<<blocks, 256, 0, stream>>>(x, iw, ib, smu, ssig, sw,
                                                    serev, smask, sens, t0, tc);
        ltc_scan_kernel<<<BB, 64, 0, stream>>>(mu, sigma, w, erev, mask, gleak,
                                               vleak, cm, ow, ob, sens, outbuf,
                                               vstate, t0, tc, t0 == 0 ? 1 : 0);
    }
    ltc_fc_kernel<<<BB * NCLASS, 64, 0, stream>>>(outbuf, fcw, fcb, out);
}